// Round 2
// baseline (7351.051 us; speedup 1.0000x reference)
//
#include <hip/hip_runtime.h>
#include <hip/hip_bf16.h>

// Problem constants (B, L, D, N) from the reference.
constexpr int Bb = 2;
constexpr int Ll = 2048;
constexpr int Dd = 1024;
constexpr int Nn = 16;

__device__ inline void store_out(float* p, float v) { *p = v; }
__device__ inline void store_out(__hip_bfloat16* p, float v) { *p = __float2bfloat16(v); }

// C[M,N] = A[M,K] @ W[N,K]^T + bias   (EP==1: += bias2, then softplus)
// 64x64 output tile per block, BK=16, 256 threads, 4x4 micro-tile per thread.
template <int EP, typename OutT>
__global__ __launch_bounds__(256) void gemm_kernel(
    const float* __restrict__ A, const float* __restrict__ W,
    const float* __restrict__ bias, const float* __restrict__ bias2,
    OutT* __restrict__ C, int M, int N, int K)
{
    __shared__ float As[16][65];   // [k][m], +1 pad breaks bank conflicts
    __shared__ float Ws[16][65];   // [k][n]

    const int bm = blockIdx.y * 64;
    const int bn = blockIdx.x * 64;
    const int tid = threadIdx.x;
    const int tm = (tid >> 4) << 2;   // 0..60
    const int tn = (tid & 15) << 2;   // 0..60
    // staging: each thread loads one float4 of A-tile and one of W-tile
    const int lr = tid >> 2;          // 0..63 (row within tile)
    const int lc = (tid & 3) << 2;    // 0,4,8,12 (k within tile)

    float acc[4][4] = {{0.f}};

    for (int k0 = 0; k0 < K; k0 += 16) {
        float4 av = *(const float4*)(A + (size_t)(bm + lr) * K + (k0 + lc));
        float4 wv = *(const float4*)(W + (size_t)(bn + lr) * K + (k0 + lc));
        __syncthreads();   // previous iteration's LDS reads done
        As[lc + 0][lr] = av.x; As[lc + 1][lr] = av.y;
        As[lc + 2][lr] = av.z; As[lc + 3][lr] = av.w;
        Ws[lc + 0][lr] = wv.x; Ws[lc + 1][lr] = wv.y;
        Ws[lc + 2][lr] = wv.z; Ws[lc + 3][lr] = wv.w;
        __syncthreads();
#pragma unroll
        for (int kk = 0; kk < 16; ++kk) {
            const float a0 = As[kk][tm + 0], a1 = As[kk][tm + 1];
            const float a2 = As[kk][tm + 2], a3 = As[kk][tm + 3];
            const float w0 = Ws[kk][tn + 0], w1 = Ws[kk][tn + 1];
            const float w2 = Ws[kk][tn + 2], w3 = Ws[kk][tn + 3];
            acc[0][0] += a0 * w0; acc[0][1] += a0 * w1; acc[0][2] += a0 * w2; acc[0][3] += a0 * w3;
            acc[1][0] += a1 * w0; acc[1][1] += a1 * w1; acc[1][2] += a1 * w2; acc[1][3] += a1 * w3;
            acc[2][0] += a2 * w0; acc[2][1] += a2 * w1; acc[2][2] += a2 * w2; acc[2][3] += a2 * w3;
            acc[3][0] += a3 * w0; acc[3][1] += a3 * w1; acc[3][2] += a3 * w2; acc[3][3] += a3 * w3;
        }
    }

#pragma unroll
    for (int i = 0; i < 4; ++i) {
#pragma unroll
        for (int j = 0; j < 4; ++j) {
            const int col = bn + tn + j;
            float v = acc[i][j] + bias[col];
            if (EP == 1) {
                v += bias2[col];
                // stable softplus
                v = (v > 20.f) ? v : log1pf(__expf(v));
            }
            store_out(&C[(size_t)(bm + tm + i) * N + col], v);
        }
    }
}

// Sequential scan over `steps` timesteps starting at global offset l0.
// One 16-lane group per (b,d) channel; lane = state index n.
// Chunk buffers are laid out [b][l_local][d][(n)] with l_local in [0, CL).
// h state (Bb*Dd*Nn floats) persists across chunk launches in workspace;
// first chunk (l0==0) starts from h=0 (workspace is poisoned each call).
__global__ __launch_bounds__(256) void scan_kernel(
    const float* __restrict__ u, const float* __restrict__ dt_c,
    const __hip_bfloat16* __restrict__ Bt_c, const __hip_bfloat16* __restrict__ Ct_c,
    const float* __restrict__ log_A, const float* __restrict__ D_skip,
    float* __restrict__ y, float* __restrict__ h_state,
    int l0, int steps, int CL)
{
    const int tid = threadIdx.x;
    const int g = tid >> 4;               // group within block (16 groups)
    const int n = tid & 15;               // state index
    const int ch = blockIdx.x * 16 + g;   // 0..2047  (= b*Dd + d)
    const int b = ch / Dd;
    const int d = ch % Dd;

    const float A = -__expf(log_A[d * Nn + n]);   // A < 0
    const float rA = 1.f / A;
    const float Dskip = D_skip[d];

    size_t idx_g = ((size_t)b * Ll + l0) * Dd + d;          // u / y (global)
    size_t idx_dt = ((size_t)b * CL) * Dd + d;              // dt chunk
    size_t idx_bn = (((size_t)b * CL) * Dd + d) * Nn + n;   // Bt/Ct chunk

    float h = (l0 == 0) ? 0.f : h_state[(size_t)ch * Nn + n];

    for (int l = 0; l < steps; ++l) {
        const float dtv = dt_c[idx_dt];
        const float uv = u[idx_g];
        const float bv = __bfloat162float(Bt_c[idx_bn]);
        const float cv = __bfloat162float(Ct_c[idx_bn]);

        const float a = __expf(dtv * A);
        const float x = (a - 1.f) * rA * bv * uv;
        h = a * h + x;
        float p = cv * h;
        // reduce over the 16-lane group (xor masks stay within the group)
        p += __shfl_xor(p, 1);
        p += __shfl_xor(p, 2);
        p += __shfl_xor(p, 4);
        p += __shfl_xor(p, 8);
        if (n == 0) y[idx_g] = p + Dskip * uv;

        idx_g  += Dd;
        idx_dt += Dd;
        idx_bn += (size_t)Dd * Nn;
    }

    h_state[(size_t)ch * Nn + n] = h;
}

extern "C" void kernel_launch(void* const* d_in, const int* in_sizes, int n_in,
                              void* d_out, int out_size, void* d_ws, size_t ws_size,
                              hipStream_t stream) {
    const float* u       = (const float*)d_in[0];
    const float* log_A   = (const float*)d_in[1];
    const float* D_skip  = (const float*)d_in[2];
    const float* dt_bias = (const float*)d_in[3];
    const float* W_dt    = (const float*)d_in[4];
    const float* b_dt    = (const float*)d_in[5];
    const float* W_B     = (const float*)d_in[6];
    const float* b_B     = (const float*)d_in[7];
    const float* W_C     = (const float*)d_in[8];
    const float* b_C     = (const float*)d_in[9];
    float* y = (float*)d_out;

    // ---- workspace budget (adaptive chunking over L) ----
    // per-timestep bytes (both batches): dt fp32 (4*D) + Bt/Ct bf16 (2*2*D*N)
    const size_t h_bytes = 256 * 1024;  // h state: 128 KB used, 256 KB reserved
    const size_t per_l = 2 * ((size_t)Dd * 4 + 2 * (size_t)Dd * Nn * 2);  // 139264
    long avail = (long)ws_size - (long)h_bytes;
    int CL = (int)(avail / (long)per_l);
    CL = (CL / 64) * 64;
    if (CL > Ll) CL = Ll;
    if (CL < 64) CL = 64;   // minimum viable; harness ws should cover ~9 MB

    char* ws = (char*)d_ws;
    float* h_state = (float*)ws;
    float* dt_c = (float*)(ws + h_bytes);
    __hip_bfloat16* Bt_c = (__hip_bfloat16*)(ws + h_bytes + (size_t)2 * CL * Dd * 4);
    __hip_bfloat16* Ct_c = Bt_c + (size_t)2 * CL * Dd * Nn;

    dim3 blk(256);
    for (int l0 = 0; l0 < Ll; l0 += CL) {
        const int steps = (Ll - l0 < CL) ? (Ll - l0) : CL;   // multiple of 64
        for (int b = 0; b < Bb; ++b) {
            const float* Ab = u + ((size_t)b * Ll + l0) * Dd;
            // dt = softplus(u @ W_dt^T + b_dt + dt_bias)
            gemm_kernel<1, float><<<dim3(Dd / 64, steps / 64), blk, 0, stream>>>(
                Ab, W_dt, b_dt, dt_bias, dt_c + (size_t)b * CL * Dd,
                steps, Dd, Dd);
            // Bt = u @ W_B^T + b_B   (col = d*16 + n, matches reshape(b,l,d,n))
            gemm_kernel<0, __hip_bfloat16><<<dim3(Dd * Nn / 64, steps / 64), blk, 0, stream>>>(
                Ab, W_B, b_B, nullptr, Bt_c + (size_t)b * CL * Dd * Nn,
                steps, Dd * Nn, Dd);
            // Ct = u @ W_C^T + b_C
            gemm_kernel<0, __hip_bfloat16><<<dim3(Dd * Nn / 64, steps / 64), blk, 0, stream>>>(
                Ab, W_C, b_C, nullptr, Ct_c + (size_t)b * CL * Dd * Nn,
                steps, Dd * Nn, Dd);
        }
        // advance all 2048 (b,d) channels by `steps` timesteps
        scan_kernel<<<dim3(Bb * Dd / 16), blk, 0, stream>>>(
            u, dt_c, Bt_c, Ct_c, log_A, D_skip, y, h_state, l0, steps, CL);
    }
}

// Round 3
// 979.454 us; speedup vs baseline: 7.5053x; 7.5053x over previous
//
#include <hip/hip_runtime.h>
#include <hip/hip_bf16.h>
#include <stdint.h>

// Problem constants
constexpr int Bb = 2;
constexpr int Ll = 2048;
constexpr int Dd = 1024;
constexpr int Nn = 16;
constexpr int NB = Dd * Nn;   // 16384, out-features of B/C projections
constexpr int SL = 64;        // scan segment length
constexpr int NCH = Bb * Dd;  // 2048 channels

typedef __bf16 bf16_t;
typedef __bf16 bf16x8 __attribute__((ext_vector_type(8)));
typedef __bf16 bf16x4 __attribute__((ext_vector_type(4)));
typedef float f32x4 __attribute__((ext_vector_type(4)));

// ---------- fp32 -> bf16 conversion (vectorized, grid-stride) ----------
__global__ __launch_bounds__(256) void cvt_bf16(const float* __restrict__ s,
                                                bf16_t* __restrict__ d, int n4) {
    int i = blockIdx.x * 256 + threadIdx.x;
    const int stride = gridDim.x * 256;
    const float4* s4 = (const float4*)s;
    bf16x4* d4 = (bf16x4*)d;
    for (; i < n4; i += stride) {
        float4 v = s4[i];
        bf16x4 o = {(bf16_t)v.x, (bf16_t)v.y, (bf16_t)v.z, (bf16_t)v.w};
        d4[i] = o;
    }
}

// ---------- bf16 MFMA GEMM: C[2*CL, NB] = A @ W^T + bias ----------
// A rows come from u_bf[Bb*Ll, Dd], rows [l0, l0+CL) of each batch fused
// batch-major. 128x128 tile, 4 waves, each wave 64x64 via 4x4 MFMA 16x16x32.
// LDS row stride 40 elems (80 B) -> uniform bank spread for ds_read_b128.
__global__ __launch_bounds__(256) void gemm_mfma_bt(
    const bf16_t* __restrict__ Abase, int CL, int l0,
    const bf16_t* __restrict__ W, const float* __restrict__ bias,
    bf16_t* __restrict__ C)
{
    constexpr int K = Dd;
    constexpr int N = NB;
    __shared__ bf16_t As[128][40];
    __shared__ bf16_t Bs[128][40];

    const int tid = threadIdx.x;
    const int bn = blockIdx.x * 128;
    const int rglob = blockIdx.y * 128;          // CL >= 128 -> block within one batch
    const int batch = rglob / CL;
    const int rin = rglob % CL;
    const bf16_t* Ap = Abase + ((size_t)batch * Ll + l0 + rin) * K;
    bf16_t* Cp = C + (size_t)rglob * N;

    const int sr = tid >> 2;          // staging row 0..63
    const int sk = (tid & 3) << 3;    // staging k offset 0,8,16,24
    const int wid = tid >> 6;
    const int lane = tid & 63;
    const int wm = (wid & 1) << 6;
    const int wn = (wid >> 1) << 6;
    const int lr = lane & 15;
    const int lq = lane >> 4;

    f32x4 acc[4][4] = {};

    for (int k0 = 0; k0 < K; k0 += 32) {
        bf16x8 a0 = *(const bf16x8*)(Ap + (size_t)sr * K + k0 + sk);
        bf16x8 a1 = *(const bf16x8*)(Ap + (size_t)(sr + 64) * K + k0 + sk);
        bf16x8 w0 = *(const bf16x8*)(W + (size_t)(bn + sr) * K + k0 + sk);
        bf16x8 w1 = *(const bf16x8*)(W + (size_t)(bn + sr + 64) * K + k0 + sk);
        __syncthreads();                 // prior iteration's LDS reads done
        *(bf16x8*)&As[sr][sk] = a0;
        *(bf16x8*)&As[sr + 64][sk] = a1;
        *(bf16x8*)&Bs[sr][sk] = w0;
        *(bf16x8*)&Bs[sr + 64][sk] = w1;
        __syncthreads();

        bf16x8 af[4], bfr[4];
#pragma unroll
        for (int mi = 0; mi < 4; ++mi)
            af[mi] = *(const bf16x8*)&As[wm + mi * 16 + lr][lq * 8];
#pragma unroll
        for (int ni = 0; ni < 4; ++ni)
            bfr[ni] = *(const bf16x8*)&Bs[wn + ni * 16 + lr][lq * 8];
#pragma unroll
        for (int mi = 0; mi < 4; ++mi)
#pragma unroll
            for (int ni = 0; ni < 4; ++ni)
                acc[mi][ni] = __builtin_amdgcn_mfma_f32_16x16x32_bf16(
                    af[mi], bfr[ni], acc[mi][ni], 0, 0, 0);
    }

    // C/D layout: col = lane&15, row = (lane>>4)*4 + i  (m89/m91-verified)
#pragma unroll
    for (int ni = 0; ni < 4; ++ni) {
        const int col = bn + wn + ni * 16 + lr;
        const float bc = bias[col];
#pragma unroll
        for (int mi = 0; mi < 4; ++mi)
#pragma unroll
            for (int i = 0; i < 4; ++i)
                Cp[(size_t)(wm + mi * 16 + lq * 4 + i) * N + col] =
                    (bf16_t)(acc[mi][ni][i] + bc);
    }
}

// ---------- fp32 GEMM for dt (kept fp32 for exp-sensitivity) ----------
// C[2*CL, Dd] = softplus(A @ W^T + b1 + b2), A rows fused like above.
__global__ __launch_bounds__(256) void gemm_dt(
    const float* __restrict__ u, int CL, int l0,
    const float* __restrict__ W, const float* __restrict__ b1,
    const float* __restrict__ b2, float* __restrict__ C)
{
    constexpr int K = Dd;
    constexpr int N = Dd;
    __shared__ float As[16][65];
    __shared__ float Ws[16][65];

    const int rglob = blockIdx.y * 64;
    const int batch = rglob / CL;
    const int rin = rglob % CL;
    const float* Ap = u + ((size_t)batch * Ll + l0 + rin) * K;
    const int bn = blockIdx.x * 64;
    const int tid = threadIdx.x;
    const int tm = (tid >> 4) << 2;
    const int tn = (tid & 15) << 2;
    const int lr = tid >> 2;
    const int lc = (tid & 3) << 2;

    float acc[4][4] = {{0.f}};

    for (int k0 = 0; k0 < K; k0 += 16) {
        float4 av = *(const float4*)(Ap + (size_t)lr * K + (k0 + lc));
        float4 wv = *(const float4*)(W + (size_t)(bn + lr) * K + (k0 + lc));
        __syncthreads();
        As[lc + 0][lr] = av.x; As[lc + 1][lr] = av.y;
        As[lc + 2][lr] = av.z; As[lc + 3][lr] = av.w;
        Ws[lc + 0][lr] = wv.x; Ws[lc + 1][lr] = wv.y;
        Ws[lc + 2][lr] = wv.z; Ws[lc + 3][lr] = wv.w;
        __syncthreads();
#pragma unroll
        for (int kk = 0; kk < 16; ++kk) {
            const float a0 = As[kk][tm + 0], a1 = As[kk][tm + 1];
            const float a2 = As[kk][tm + 2], a3 = As[kk][tm + 3];
            const float w0 = Ws[kk][tn + 0], w1 = Ws[kk][tn + 1];
            const float w2 = Ws[kk][tn + 2], w3 = Ws[kk][tn + 3];
            acc[0][0] += a0 * w0; acc[0][1] += a0 * w1; acc[0][2] += a0 * w2; acc[0][3] += a0 * w3;
            acc[1][0] += a1 * w0; acc[1][1] += a1 * w1; acc[1][2] += a1 * w2; acc[1][3] += a1 * w3;
            acc[2][0] += a2 * w0; acc[2][1] += a2 * w1; acc[2][2] += a2 * w2; acc[2][3] += a2 * w3;
            acc[3][0] += a3 * w0; acc[3][1] += a3 * w1; acc[3][2] += a3 * w2; acc[3][3] += a3 * w3;
        }
    }

#pragma unroll
    for (int i = 0; i < 4; ++i)
#pragma unroll
        for (int j = 0; j < 4; ++j) {
            const int col = bn + tn + j;
            float v = acc[i][j] + b1[col] + b2[col];
            v = (v > 20.f) ? v : log1pf(__expf(v));
            C[(size_t)(rglob + tm + i) * N + col] = v;
        }
}

// ---------- scan pass A: per-segment local scan (h0 = 0) ----------
// group (16 lanes) = (ch, s); computes p = prod(a_t), h_local over SL steps.
__global__ __launch_bounds__(256) void scan_seg_local(
    const float* __restrict__ u, const float* __restrict__ dt_c,
    const bf16_t* __restrict__ Bt_c, const float* __restrict__ log_A,
    float* __restrict__ pseg, float* __restrict__ hseg, int CL, int l0)
{
    const int tid = threadIdx.x;
    const int g = tid >> 4, n = tid & 15;
    const int gid = blockIdx.x * 16 + g;
    const int ch = gid & (NCH - 1);
    const int s = gid >> 11;          // NCH = 2048 = 1<<11
    const int b = ch >> 10, d = ch & (Dd - 1);

    const float A = -__expf(log_A[d * Nn + n]);
    const float rA = 1.f / A;

    const int rowc0 = b * CL + s * SL;
    size_t idx_dt = (size_t)rowc0 * Dd + d;
    size_t idx_bn = (size_t)rowc0 * NB + d * Nn + n;
    size_t idx_u = ((size_t)b * Ll + l0 + s * SL) * Dd + d;

    float p = 1.f, h = 0.f;
    for (int l = 0; l < SL; ++l) {
        const float dtv = dt_c[idx_dt];
        const float uv = u[idx_u];
        const float bv = (float)Bt_c[idx_bn];
        const float a = __expf(dtv * A);
        p *= a;
        h = a * h + (a - 1.f) * rA * bv * uv;
        idx_dt += Dd; idx_bn += NB; idx_u += Dd;
    }
    const size_t o = ((size_t)s * NCH + ch) * Nn + n;
    pseg[o] = p;
    hseg[o] = h;
}

// ---------- scan pass B: sequential combine across segments ----------
__global__ __launch_bounds__(256) void scan_combine(
    const float* __restrict__ pseg, const float* __restrict__ hseg,
    float* __restrict__ hin_arr, float* __restrict__ h_state,
    int NSEG, int l0)
{
    const int t = blockIdx.x * 256 + threadIdx.x;   // (ch,n), 0..32767
    float hin = (l0 == 0) ? 0.f : h_state[t];
    for (int s = 0; s < NSEG; ++s) {
        const size_t o = (size_t)s * (NCH * Nn) + t;
        hin_arr[o] = hin;
        hin = pseg[o] * hin + hseg[o];
    }
    h_state[t] = hin;
}

// ---------- scan pass C: re-run segment from correct h_in, emit y ----------
__global__ __launch_bounds__(256) void scan_seg_final(
    const float* __restrict__ u, const float* __restrict__ dt_c,
    const bf16_t* __restrict__ Bt_c, const bf16_t* __restrict__ Ct_c,
    const float* __restrict__ log_A, const float* __restrict__ D_skip,
    const float* __restrict__ hin_arr, float* __restrict__ y, int CL, int l0)
{
    const int tid = threadIdx.x;
    const int g = tid >> 4, n = tid & 15;
    const int gid = blockIdx.x * 16 + g;
    const int ch = gid & (NCH - 1);
    const int s = gid >> 11;
    const int b = ch >> 10, d = ch & (Dd - 1);

    const float A = -__expf(log_A[d * Nn + n]);
    const float rA = 1.f / A;
    const float Dsk = D_skip[d];

    const int rowc0 = b * CL + s * SL;
    size_t idx_dt = (size_t)rowc0 * Dd + d;
    size_t idx_bn = (size_t)rowc0 * NB + d * Nn + n;
    size_t idx_u = ((size_t)b * Ll + l0 + s * SL) * Dd + d;

    float h = hin_arr[((size_t)s * NCH + ch) * Nn + n];
    for (int l = 0; l < SL; ++l) {
        const float dtv = dt_c[idx_dt];
        const float uv = u[idx_u];
        const float bv = (float)Bt_c[idx_bn];
        const float cv = (float)Ct_c[idx_bn];
        const float a = __expf(dtv * A);
        h = a * h + (a - 1.f) * rA * bv * uv;
        float p = cv * h;
        p += __shfl_xor(p, 1);
        p += __shfl_xor(p, 2);
        p += __shfl_xor(p, 4);
        p += __shfl_xor(p, 8);
        if (n == 0) y[idx_u] = p + Dsk * uv;
        idx_dt += Dd; idx_bn += NB; idx_u += Dd;
    }
}

// ---------- host ----------
static inline size_t al256(size_t x) { return (x + 255) & ~(size_t)255; }

extern "C" void kernel_launch(void* const* d_in, const int* in_sizes, int n_in,
                              void* d_out, int out_size, void* d_ws, size_t ws_size,
                              hipStream_t stream) {
    const float* u       = (const float*)d_in[0];
    const float* log_A   = (const float*)d_in[1];
    const float* D_skip  = (const float*)d_in[2];
    const float* dt_bias = (const float*)d_in[3];
    const float* W_dt    = (const float*)d_in[4];
    const float* b_dt    = (const float*)d_in[5];
    const float* W_B     = (const float*)d_in[6];
    const float* b_B     = (const float*)d_in[7];
    const float* W_C     = (const float*)d_in[8];
    const float* b_C     = (const float*)d_in[9];
    float* y = (float*)d_out;

    // fixed buffers
    const size_t sz_ubf = al256((size_t)Bb * Ll * Dd * 2);   // 8.4 MB
    const size_t sz_w   = al256((size_t)NB * Dd * 2);        // 33.6 MB each
    const size_t sz_h   = al256((size_t)NCH * Nn * 4);       // 128 KB

    // choose CL (chunk length, divides Ll, >=128 so GEMM blocks stay in-batch)
    int CL = 128;
    const int cands[5] = {2048, 1024, 512, 256, 128};
    for (int i = 0; i < 5; ++i) {
        const int c = cands[i];
        const int nseg = c / SL;
        const size_t seg = 3 * al256((size_t)nseg * NCH * Nn * 4);
        const size_t chunk = al256((size_t)2 * c * Dd * 4)        // dt
                           + 2 * al256((size_t)2 * c * NB * 2);   // Bt, Ct
        if (sz_ubf + 2 * sz_w + sz_h + seg + chunk <= ws_size) { CL = c; break; }
    }
    const int NSEG = CL / SL;

    // bump-allocate workspace
    char* p = (char*)d_ws;
    bf16_t* u_bf  = (bf16_t*)p; p += sz_ubf;
    bf16_t* wB_bf = (bf16_t*)p; p += sz_w;
    bf16_t* wC_bf = (bf16_t*)p; p += sz_w;
    float* h_state = (float*)p; p += sz_h;
    const size_t sz_seg1 = al256((size_t)NSEG * NCH * Nn * 4);
    float* pseg    = (float*)p; p += sz_seg1;
    float* hseg    = (float*)p; p += sz_seg1;
    float* hin_arr = (float*)p; p += sz_seg1;
    float* dt_c    = (float*)p; p += al256((size_t)2 * CL * Dd * 4);
    bf16_t* Bt_c   = (bf16_t*)p; p += al256((size_t)2 * CL * NB * 2);
    bf16_t* Ct_c   = (bf16_t*)p;

    // one-time conversions to bf16
    cvt_bf16<<<2048, 256, 0, stream>>>(u, u_bf, Bb * Ll * Dd / 4);
    cvt_bf16<<<2048, 256, 0, stream>>>(W_B, wB_bf, NB * Dd / 4);
    cvt_bf16<<<2048, 256, 0, stream>>>(W_C, wC_bf, NB * Dd / 4);

    for (int l0 = 0; l0 < Ll; l0 += CL) {
        gemm_dt<<<dim3(Dd / 64, 2 * CL / 64), 256, 0, stream>>>(
            u, CL, l0, W_dt, b_dt, dt_bias, dt_c);
        gemm_mfma_bt<<<dim3(NB / 128, 2 * CL / 128), 256, 0, stream>>>(
            u_bf, CL, l0, wB_bf, b_B, Bt_c);
        gemm_mfma_bt<<<dim3(NB / 128, 2 * CL / 128), 256, 0, stream>>>(
            u_bf, CL, l0, wC_bf, b_C, Ct_c);
        scan_seg_local<<<dim3(128 * NSEG), 256, 0, stream>>>(
            u, dt_c, Bt_c, log_A, pseg, hseg, CL, l0);
        scan_combine<<<dim3(128), 256, 0, stream>>>(
            pseg, hseg, hin_arr, h_state, NSEG, l0);
        scan_seg_final<<<dim3(128 * NSEG), 256, 0, stream>>>(
            u, dt_c, Bt_c, Ct_c, log_A, D_skip, hin_arr, y, CL, l0);
    }
}

// Round 4
// 800.041 us; speedup vs baseline: 9.1883x; 1.2243x over previous
//
#include <hip/hip_runtime.h>
#include <hip/hip_bf16.h>
#include <stdint.h>

// Problem constants
constexpr int Bb = 2;
constexpr int Ll = 2048;
constexpr int Dd = 1024;
constexpr int Nn = 16;
constexpr int NB = Dd * Nn;    // 16384
constexpr int SL = 64;         // scan segment length
constexpr int NCH = Bb * Dd;   // 2048 channels
constexpr int KCAT = 3 * Dd;   // 3072: [hi|lo|hi] x [Whi|Whi|Wlo]

typedef __bf16 bf16_t;
typedef __bf16 bf16x8 __attribute__((ext_vector_type(8)));
typedef __bf16 bf16x4 __attribute__((ext_vector_type(4)));
typedef float f32x4 __attribute__((ext_vector_type(4)));

// async global->LDS, 16 B per lane. LDS dest = wave-uniform base + lane*16
// (m104/m108); passing per-lane ptr base+lane*16 matches that exactly.
__device__ inline void gld_lds16(const void* g, void* l) {
    __builtin_amdgcn_global_load_lds(
        (const __attribute__((address_space(1))) unsigned int*)g,
        (__attribute__((address_space(3))) unsigned int*)l, 16, 0, 0);
}

// ---------- fp32 -> bf16 conversion (vectorized, grid-stride) ----------
__global__ __launch_bounds__(256) void cvt_bf16(const float* __restrict__ s,
                                                bf16_t* __restrict__ d, int n4) {
    int i = blockIdx.x * 256 + threadIdx.x;
    const int stride = gridDim.x * 256;
    const float4* s4 = (const float4*)s;
    bf16x4* d4 = (bf16x4*)d;
    for (; i < n4; i += stride) {
        float4 v = s4[i];
        bf16x4 o = {(bf16_t)v.x, (bf16_t)v.y, (bf16_t)v.z, (bf16_t)v.w};
        d4[i] = o;
    }
}

// u_cat row = [u_hi (1024) | u_lo (1024) | u_hi (1024)], one thread per float4
__global__ __launch_bounds__(256) void build_ucat(const float* __restrict__ u,
                                                  bf16_t* __restrict__ ucat) {
    const int i = blockIdx.x * 256 + threadIdx.x;   // 0 .. 4096*256-1
    const int row = i >> 8;
    const int c = (i & 255) << 2;
    float4 v = ((const float4*)u)[i];
    bf16x4 hi = {(bf16_t)v.x, (bf16_t)v.y, (bf16_t)v.z, (bf16_t)v.w};
    bf16x4 lo = {(bf16_t)(v.x - (float)hi.x), (bf16_t)(v.y - (float)hi.y),
                 (bf16_t)(v.z - (float)hi.z), (bf16_t)(v.w - (float)hi.w)};
    bf16_t* r = ucat + (size_t)row * KCAT;
    *(bf16x4*)(r + c) = hi;
    *(bf16x4*)(r + Dd + c) = lo;
    *(bf16x4*)(r + 2 * Dd + c) = hi;
}

// W_cat row = [W_hi | W_hi | W_lo]
__global__ __launch_bounds__(256) void build_wcat(const float* __restrict__ w,
                                                  bf16_t* __restrict__ wcat) {
    const int i = blockIdx.x * 256 + threadIdx.x;   // 0 .. 1024*256-1
    const int row = i >> 8;
    const int c = (i & 255) << 2;
    float4 v = ((const float4*)w)[i];
    bf16x4 hi = {(bf16_t)v.x, (bf16_t)v.y, (bf16_t)v.z, (bf16_t)v.w};
    bf16x4 lo = {(bf16_t)(v.x - (float)hi.x), (bf16_t)(v.y - (float)hi.y),
                 (bf16_t)(v.z - (float)hi.z), (bf16_t)(v.w - (float)hi.w)};
    bf16_t* r = wcat + (size_t)row * KCAT;
    *(bf16x4*)(r + c) = hi;
    *(bf16x4*)(r + Dd + c) = hi;
    *(bf16x4*)(r + 2 * Dd + c) = lo;
}

// ---------- bf16 MFMA GEMM, global_load_lds staging (m97 pattern) ----------
// C[rows, N] = A @ W^T (+bias / +softplus epilogue). 128x128 tile, 4 waves,
// each wave 64x64 via 4x4 mfma_f32_16x16x32_bf16. LDS unpadded [128][32]:
// thread tid's 16B staging chunk lands at byte tid*16 (+4096 for rows 64..127),
// i.e. row sr=tid>>2, k-chunk (tid&3)*8 — same content as a [row][k] tile.
// Row mapping: rglob -> (rglob/CL)*Ll + l0 + rglob%CL  (blocks never straddle
// batches since CL%128==0).
template <int EP, typename OutT>
__global__ __launch_bounds__(256) void gemm_mfma(
    const bf16_t* __restrict__ Abase, int CL, int l0, int K,
    const bf16_t* __restrict__ W, const float* __restrict__ b1,
    const float* __restrict__ b2, OutT* __restrict__ C, int N)
{
    __shared__ bf16_t As[128 * 32];
    __shared__ bf16_t Bs[128 * 32];

    const int tid = threadIdx.x;
    const int bn = blockIdx.x * 128;
    const int rglob = blockIdx.y * 128;
    const int batch = rglob / CL;
    const int rin = rglob % CL;
    const bf16_t* Ap = Abase + ((size_t)batch * Ll + l0 + rin) * K;
    const bf16_t* Wp = W + (size_t)bn * K;
    OutT* Cp = C + (size_t)rglob * N;

    const int sr = tid >> 2;          // staging row 0..63
    const int sc = (tid & 3) << 3;    // staging k offset (bf16 elems)
    char* ldsA = (char*)As + tid * 16;
    char* ldsB = (char*)Bs + tid * 16;

    const int lane = tid & 63;
    const int wid = tid >> 6;
    const int wm = (wid & 1) << 6;
    const int wn = (wid >> 1) << 6;
    const int lr = lane & 15;
    const int lq = lane >> 4;

    f32x4 acc[4][4] = {};

    for (int k0 = 0; k0 < K; k0 += 32) {
        __syncthreads();   // prior iteration's LDS reads done
        gld_lds16(Ap + (size_t)sr * K + k0 + sc, ldsA);
        gld_lds16(Ap + (size_t)(sr + 64) * K + k0 + sc, ldsA + 4096);
        gld_lds16(Wp + (size_t)sr * K + k0 + sc, ldsB);
        gld_lds16(Wp + (size_t)(sr + 64) * K + k0 + sc, ldsB + 4096);
        __syncthreads();   // drains vmcnt (compiler emits waitcnt before barrier)

        bf16x8 af[4], bfr[4];
#pragma unroll
        for (int mi = 0; mi < 4; ++mi)
            af[mi] = *(const bf16x8*)&As[(wm + mi * 16 + lr) * 32 + lq * 8];
#pragma unroll
        for (int ni = 0; ni < 4; ++ni)
            bfr[ni] = *(const bf16x8*)&Bs[(wn + ni * 16 + lr) * 32 + lq * 8];
#pragma unroll
        for (int mi = 0; mi < 4; ++mi)
#pragma unroll
            for (int ni = 0; ni < 4; ++ni)
                acc[mi][ni] = __builtin_amdgcn_mfma_f32_16x16x32_bf16(
                    af[mi], bfr[ni], acc[mi][ni], 0, 0, 0);
    }

    // C/D layout: col = lane&15, row = (lane>>4)*4 + i  (m89/m91-verified)
#pragma unroll
    for (int ni = 0; ni < 4; ++ni) {
        const int col = bn + wn + ni * 16 + lr;
        const float bc = b1[col] + (EP == 1 ? b2[col] : 0.f);
#pragma unroll
        for (int mi = 0; mi < 4; ++mi)
#pragma unroll
            for (int i = 0; i < 4; ++i) {
                float v = acc[mi][ni][i] + bc;
                if (EP == 1) v = (v > 20.f) ? v : log1pf(__expf(v));
                Cp[(size_t)(wm + mi * 16 + lq * 4 + i) * N + col] = (OutT)v;
            }
    }
}

// ---------- scan pass A: per-segment local scan (h0 = 0) ----------
__global__ __launch_bounds__(256) void scan_seg_local(
    const float* __restrict__ u, const float* __restrict__ dt,
    const bf16_t* __restrict__ Bt_c, const float* __restrict__ log_A,
    float* __restrict__ pseg, float* __restrict__ hseg, int CL, int l0)
{
    const int tid = threadIdx.x;
    const int g = tid >> 4, n = tid & 15;
    const int gid = blockIdx.x * 16 + g;
    const int ch = gid & (NCH - 1);
    const int s = gid >> 11;
    const int b = ch >> 10, d = ch & (Dd - 1);

    const float A = -__expf(log_A[d * Nn + n]);
    const float rA = 1.f / A;

    size_t idx_bn = (size_t)(b * CL + s * SL) * NB + d * Nn + n;
    size_t idx_u = ((size_t)b * Ll + l0 + s * SL) * Dd + d;   // u/dt global [B,L,D]

    float p = 1.f, h = 0.f;
    for (int l = 0; l < SL; ++l) {
        const float dtv = dt[idx_u];
        const float uv = u[idx_u];
        const float bv = (float)Bt_c[idx_bn];
        const float a = __expf(dtv * A);
        p *= a;
        h = a * h + (a - 1.f) * rA * bv * uv;
        idx_bn += NB; idx_u += Dd;
    }
    const size_t o = ((size_t)s * NCH + ch) * Nn + n;
    pseg[o] = p;
    hseg[o] = h;
}

// ---------- scan pass B: sequential combine across segments ----------
__global__ __launch_bounds__(256) void scan_combine(
    const float* __restrict__ pseg, const float* __restrict__ hseg,
    float* __restrict__ hin_arr, float* __restrict__ h_state,
    int NSEG, int l0)
{
    const int t = blockIdx.x * 256 + threadIdx.x;   // (ch,n), 0..32767
    float hin = (l0 == 0) ? 0.f : h_state[t];
    for (int s = 0; s < NSEG; ++s) {
        const size_t o = (size_t)s * (NCH * Nn) + t;
        hin_arr[o] = hin;
        hin = pseg[o] * hin + hseg[o];
    }
    h_state[t] = hin;
}

// ---------- scan pass C: re-run segment from correct h_in, emit y ----------
__global__ __launch_bounds__(256) void scan_seg_final(
    const float* __restrict__ u, const float* __restrict__ dt,
    const bf16_t* __restrict__ Bt_c, const bf16_t* __restrict__ Ct_c,
    const float* __restrict__ log_A, const float* __restrict__ D_skip,
    const float* __restrict__ hin_arr, float* __restrict__ y, int CL, int l0)
{
    const int tid = threadIdx.x;
    const int g = tid >> 4, n = tid & 15;
    const int gid = blockIdx.x * 16 + g;
    const int ch = gid & (NCH - 1);
    const int s = gid >> 11;
    const int b = ch >> 10, d = ch & (Dd - 1);

    const float A = -__expf(log_A[d * Nn + n]);
    const float rA = 1.f / A;
    const float Dsk = D_skip[d];

    size_t idx_bn = (size_t)(b * CL + s * SL) * NB + d * Nn + n;
    size_t idx_u = ((size_t)b * Ll + l0 + s * SL) * Dd + d;

    float h = hin_arr[((size_t)s * NCH + ch) * Nn + n];
    for (int l = 0; l < SL; ++l) {
        const float dtv = dt[idx_u];
        const float uv = u[idx_u];
        const float bv = (float)Bt_c[idx_bn];
        const float cv = (float)Ct_c[idx_bn];
        const float a = __expf(dtv * A);
        h = a * h + (a - 1.f) * rA * bv * uv;
        float p = cv * h;
        p += __shfl_xor(p, 1);
        p += __shfl_xor(p, 2);
        p += __shfl_xor(p, 4);
        p += __shfl_xor(p, 8);
        if (n == 0) y[idx_u] = p + Dsk * uv;
        idx_bn += NB; idx_u += Dd;
    }
}

// ---------- host ----------
static inline size_t al256(size_t x) { return (x + 255) & ~(size_t)255; }

extern "C" void kernel_launch(void* const* d_in, const int* in_sizes, int n_in,
                              void* d_out, int out_size, void* d_ws, size_t ws_size,
                              hipStream_t stream) {
    const float* u       = (const float*)d_in[0];
    const float* log_A   = (const float*)d_in[1];
    const float* D_skip  = (const float*)d_in[2];
    const float* dt_bias = (const float*)d_in[3];
    const float* W_dt    = (const float*)d_in[4];
    const float* b_dt    = (const float*)d_in[5];
    const float* W_B     = (const float*)d_in[6];
    const float* b_B     = (const float*)d_in[7];
    const float* W_C     = (const float*)d_in[8];
    const float* b_C     = (const float*)d_in[9];
    float* y = (float*)d_out;

    // fixed buffers
    const size_t sz_ubf  = al256((size_t)Bb * Ll * Dd * 2);      // 8.4 MB
    const size_t sz_w    = al256((size_t)NB * Dd * 2);           // 33.6 MB x2
    const size_t sz_h    = al256((size_t)NCH * Nn * 4);          // 128 KB
    const size_t sz_dtf  = al256((size_t)Bb * Ll * Dd * 4);      // 16.8 MB
    const size_t sz_ucat = al256((size_t)Bb * Ll * KCAT * 2);    // 25.2 MB (overlay)
    const size_t sz_wcat = al256((size_t)Dd * KCAT * 2);         // 6.3 MB (overlay)

    // choose CL: fixed + seg buffers + max(chunk Bt/Ct, overlay ucat+wcat)
    int CL = 128;
    const int cands[5] = {2048, 1024, 512, 256, 128};
    for (int i = 0; i < 5; ++i) {
        const int c = cands[i];
        const int nseg = c / SL;
        const size_t seg = 3 * al256((size_t)nseg * NCH * Nn * 4);
        const size_t chunk = 2 * al256((size_t)2 * c * NB * 2);
        const size_t ovl = sz_ucat + sz_wcat;
        const size_t need = sz_ubf + 2 * sz_w + sz_h + sz_dtf + seg +
                            (chunk > ovl ? chunk : ovl);
        if (need <= ws_size) { CL = c; break; }
    }
    const int NSEG = CL / SL;

    // bump-allocate
    char* p = (char*)d_ws;
    bf16_t* u_bf   = (bf16_t*)p; p += sz_ubf;
    bf16_t* wB_bf  = (bf16_t*)p; p += sz_w;
    bf16_t* wC_bf  = (bf16_t*)p; p += sz_w;
    float* h_state = (float*)p; p += sz_h;
    float* dt_full = (float*)p; p += sz_dtf;
    const size_t sz_seg1 = al256((size_t)NSEG * NCH * Nn * 4);
    float* pseg    = (float*)p; p += sz_seg1;
    float* hseg    = (float*)p; p += sz_seg1;
    float* hin_arr = (float*)p; p += sz_seg1;
    // chunk region (Bt_c/Ct_c) overlaid with u_cat/W_cat (dead after dt GEMM)
    char* chunk0 = p;
    bf16_t* Bt_c = (bf16_t*)chunk0;
    bf16_t* Ct_c = (bf16_t*)(chunk0 + al256((size_t)2 * CL * NB * 2));
    bf16_t* u_cat = (bf16_t*)chunk0;
    bf16_t* w_cat = (bf16_t*)(chunk0 + sz_ucat);

    // conversions
    cvt_bf16<<<2048, 256, 0, stream>>>(u, u_bf, Bb * Ll * Dd / 4);
    cvt_bf16<<<2048, 256, 0, stream>>>(W_B, wB_bf, NB * Dd / 4);
    cvt_bf16<<<2048, 256, 0, stream>>>(W_C, wC_bf, NB * Dd / 4);
    build_ucat<<<Bb * Ll * Dd / 4 / 256, 256, 0, stream>>>(u, u_cat);
    build_wcat<<<Dd * Dd / 4 / 256, 256, 0, stream>>>(W_dt, w_cat);

    // dt for ALL of L in one MFMA GEMM (hi/lo split -> fp32-grade accuracy)
    gemm_mfma<1, float><<<dim3(Dd / 128, Bb * Ll / 128), 256, 0, stream>>>(
        u_cat, Ll, 0, KCAT, w_cat, b_dt, dt_bias, dt_full, Dd);

    for (int l0 = 0; l0 < Ll; l0 += CL) {
        gemm_mfma<0, bf16_t><<<dim3(NB / 128, 2 * CL / 128), 256, 0, stream>>>(
            u_bf, CL, l0, Dd, wB_bf, b_B, nullptr, Bt_c, NB);
        gemm_mfma<0, bf16_t><<<dim3(NB / 128, 2 * CL / 128), 256, 0, stream>>>(
            u_bf, CL, l0, Dd, wC_bf, b_C, nullptr, Ct_c, NB);
        scan_seg_local<<<dim3(128 * NSEG), 256, 0, stream>>>(
            u, dt_full, Bt_c, log_A, pseg, hseg, CL, l0);
        scan_combine<<<dim3(128), 256, 0, stream>>>(
            pseg, hseg, hin_arr, h_state, NSEG, l0);
        scan_seg_final<<<dim3(128 * NSEG), 256, 0, stream>>>(
            u, dt_full, Bt_c, Ct_c, log_A, D_skip, hin_arr, y, CL, l0);
    }
}